// Round 5
// baseline (301.208 us; speedup 1.0000x reference)
//
#include <hip/hip_runtime.h>

typedef unsigned short u16;
typedef unsigned int u32;
typedef __attribute__((ext_vector_type(8))) short bf16x8;
typedef __attribute__((ext_vector_type(4))) float f32x4;

// Problem constants
static constexpr int B = 16, C = 32, H = 192, W = 192;
static constexpr int HW = H * W;              // 36864
static constexpr int E = 8;
static constexpr int CO = 32;
static constexpr long long NTOT = (long long)B * C * HW; // 18874368
static constexpr float SILU1 = 0.7310585786300049f;      // silu(1), P0 block

// Workspace layout (bytes): t (interleaved [b][y][x][c] bf16) first
static constexpr size_t GX_OFF = (size_t)NTOT * 2;           // gate_x: 512 f
static constexpr size_t SK_OFF = GX_OFF + 512 * 4;           // Sk: 288 f
static constexpr size_t SS_OFF = SK_OFF + 288 * 4;           // Ssum: 32 f
static constexpr size_t WF_OFF = SS_OFF + 128;               // wfrag: 27648 bf16

__device__ inline u16 f2b(float f) {             // rne float->bf16 bits
    u32 u = __float_as_uint(f);
    return (u16)((u + 0x7fffu + ((u >> 16) & 1u)) >> 16);
}
__device__ inline float silu(float z) { return z / (1.0f + __expf(-z)); }
__device__ inline float fast_tanh(float v) {     // 1 - 2/(e^2v+1); sat-safe
    return 1.0f - 2.0f / (__expf(2.0f * v) + 1.0f);
}

// ---------------- init: zero gate accumulator ------------------------------
__global__ void init_gate(float* __restrict__ gate_x) {
    gate_x[threadIdx.x] = 0.0f;
}

// ---------- Kernel 1: tanh -> t interleaved [b][y][x][c] + gate partials ---
__global__ __launch_bounds__(192) void stage1(const float* __restrict__ x,
                                              u16* __restrict__ t_out,
                                              float* __restrict__ gate_x) {
    const int y = blockIdx.x, b = blockIdx.y, tx = threadIdx.x;
    const int lane = tx & 63, wv = tx >> 6;
    __shared__ float gred[32][3];
    u32 pk[16];
    #pragma unroll
    for (int cg = 0; cg < 16; ++cg) {
        float v0 = x[((size_t)(b * C + 2 * cg) * H + y) * W + tx];
        float v1 = x[((size_t)(b * C + 2 * cg + 1) * H + y) * W + tx];
        pk[cg] = (u32)f2b(fast_tanh(v0)) | ((u32)f2b(fast_tanh(v1)) << 16);
        float s0 = v0, s1 = v1;
        #pragma unroll
        for (int off = 32; off > 0; off >>= 1) {
            s0 += __shfl_down(s0, off, 64);
            s1 += __shfl_down(s1, off, 64);
        }
        if (lane == 0) { gred[2 * cg][wv] = s0; gred[2 * cg + 1][wv] = s1; }
    }
    uint4* o = (uint4*)(t_out + ((size_t)b * HW + (size_t)y * W + tx) * 32);
    const uint4* s4 = (const uint4*)pk;
    o[0] = s4[0]; o[1] = s4[1]; o[2] = s4[2]; o[3] = s4[3];
    __syncthreads();
    if (tx < 32)
        atomicAdd(&gate_x[b * C + tx],
                  (gred[tx][0] + gred[tx][1] + gred[tx][2]) * (1.0f / HW));
}

// ---------- Kernel 2: prep — wfrag bf16 B-frags + Sk/Ssum ------------------
// blocks 0..107: wfrag; block 108: Sk/Ssum.
__global__ __launch_bounds__(256) void prep(const float* __restrict__ pw,
                                            float* __restrict__ Sk,
                                            float* __restrict__ Ssum,
                                            u16* __restrict__ wfrag) {
    const int blk = blockIdx.x, t = threadIdx.x;
    if (blk < 108) {
        // B-frag: n=co=half*16+(lane&15); k=ci_local=(lane>>4)*8+e
        int j = blk * 256 + t;
        int e = j & 7, lane = (j >> 3) & 63, rest = j >> 9;
        int half = rest & 1, pt = rest >> 1;
        int p = pt / 9, tap = pt - p * 9;
        int co = half * 16 + (lane & 15);
        int ci = 32 + p * 32 + (lane >> 4) * 8 + e;
        wfrag[j] = f2b(pw[(size_t)co * 1152 + ci * 9 + tap]);
        return;
    }
    __shared__ float sred[9][32][8];
    __shared__ float sks[288];
    const int co = t & 31, sub = t >> 5;
    #pragma unroll
    for (int k = 0; k < 9; ++k) {
        float s = 0.0f;
        #pragma unroll
        for (int i = 0; i < 4; ++i)
            s += pw[(size_t)co * 1152 + (sub * 4 + i) * 9 + k];
        sred[k][co][sub] = s;
    }
    __syncthreads();
    for (int j = t; j < 288; j += 256) {
        int k = j >> 5, c = j & 31;
        float s = 0.0f;
        #pragma unroll
        for (int u = 0; u < 8; ++u) s += sred[k][c][u];
        sks[j] = s; Sk[j] = s;
    }
    __syncthreads();
    if (t < 32) {
        float s = 0.0f;
        #pragma unroll
        for (int k = 0; k < 9; ++k) s += sks[k * 32 + t];
        Ssum[t] = s;
    }
}

// ---------- Kernel 3: fused gating + silu basis + MFMA conv ----------------
// 16x16 tile, halo 18x18=324 px. 4 waves; wave w: y rows 4w..4w+3.
// t gathered once (coalesced uint4, interleaved layout) into regs; all 3 silu
// planes written to triple gtile; ONE barrier; then 648 MFMA/wave.
static constexpr int GSTR = 40;                 // u16 per pixel (80 B)

__global__ __launch_bounds__(256) void conv_mfma(const u16* __restrict__ t_ws,
                                                 const u16* __restrict__ wfrag,
                                                 const float* __restrict__ beta_w,
                                                 const float* __restrict__ gate_x,
                                                 const float* __restrict__ wg,
                                                 const float* __restrict__ Sk,
                                                 const float* __restrict__ Ssum,
                                                 float* __restrict__ out) {
    __shared__ __align__(16) u16 gtile[3][324 * GSTR];   // 77760 B
    __shared__ float lg[B][E];
    __shared__ float scl[B];

    const int b = blockIdx.z;
    const int gx0 = blockIdx.x << 4, gy0 = blockIdx.y << 4;
    const int tid = threadIdx.x;
    const int w = tid >> 6, lane = tid & 63, q = lane >> 4, ml = lane & 15;
    const float beta2 = 2.25f * beta_w[1];
    const float beta23 = beta2 + (300.0f / 9.0f) * beta_w[2];

    // pixel ownership: p0 = tid; 68 extra pixels spread 17/wave
    const int p0 = tid;
    int extra = -1;
    if ((tid & 3) == 0) extra = tid >> 2;                 // 64
    else if ((tid & 63) == 1) extra = 64 + (tid >> 6);    // +4
    const int p1 = (extra >= 0) ? 256 + extra : -1;

    // ---- phase 0: coalesced gather of t (64 B per owned pixel) ----
    u32 pk0[16], pk1[16];
    bool vv0, vv1 = false;
    {
        int py = p0 / 18, px = p0 - py * 18;
        int gy = gy0 + py - 1, gx = gx0 + px - 1;
        vv0 = (unsigned)gy < (unsigned)H && (unsigned)gx < (unsigned)W;
        if (vv0) {
            const uint4* tp = (const uint4*)(t_ws + ((size_t)b * HW + (size_t)gy * W + gx) * 32);
            uint4 a0 = tp[0], a1 = tp[1], a2 = tp[2], a3 = tp[3];
            *(uint4*)&pk0[0] = a0; *(uint4*)&pk0[4] = a1;
            *(uint4*)&pk0[8] = a2; *(uint4*)&pk0[12] = a3;
        } else {
            #pragma unroll
            for (int cc = 0; cc < 16; ++cc) pk0[cc] = 0u;
        }
        if (p1 >= 0) {
            int py1 = p1 / 18, px1 = p1 - py1 * 18;
            int gy1 = gy0 + py1 - 1, gx1 = gx0 + px1 - 1;
            vv1 = (unsigned)gy1 < (unsigned)H && (unsigned)gx1 < (unsigned)W;
            if (vv1) {
                const uint4* tp = (const uint4*)(t_ws + ((size_t)b * HW + (size_t)gy1 * W + gx1) * 32);
                uint4 a0 = tp[0], a1 = tp[1], a2 = tp[2], a3 = tp[3];
                *(uint4*)&pk1[0] = a0; *(uint4*)&pk1[4] = a1;
                *(uint4*)&pk1[8] = a2; *(uint4*)&pk1[12] = a3;
            } else {
                #pragma unroll
                for (int cc = 0; cc < 16; ++cc) pk1[cc] = 0u;
            }
        }
    }

    // ---- gating (every block; L2-hot; overlaps gather latency) ----
    if (tid < 128) {
        int gb = tid >> 3, ge = tid & 7;
        float s = 0.0f;
        #pragma unroll
        for (int c = 0; c < 32; ++c) s += gate_x[gb * 32 + c] * wg[c * 8 + ge];
        lg[gb][ge] = s;
    }
    __syncthreads();
    if (tid < 16) {
        float p[E];
        float m = lg[tid][0];
        #pragma unroll
        for (int e = 1; e < E; ++e) m = fmaxf(m, lg[tid][e]);
        float sum = 0.0f;
        #pragma unroll
        for (int e = 0; e < E; ++e) { p[e] = __expf(lg[tid][e] - m); sum += p[e]; }
        float inv = 1.0f / sum;
        #pragma unroll
        for (int e = 0; e < E; ++e) p[e] *= inv;
        int i0 = 0; float v0g = p[0];
        #pragma unroll
        for (int e = 1; e < E; ++e) if (p[e] > v0g) { v0g = p[e]; i0 = e; }
        int i1 = -1; float v1g = -1.0f;
        #pragma unroll
        for (int e = 0; e < E; ++e) { if (e == i0) continue; if (p[e] > v1g) { v1g = p[e]; i1 = e; } }
        const float denom = v0g + v1g + 1e-6f;
        const float g0 = v0g / denom, g1 = v1g / denom;
        #pragma unroll
        for (int e = 0; e < E; ++e) lg[tid][e] = 0.0f;
        lg[tid][i0] = g0; lg[tid][i1] = g1;
        scl[tid] = g0 + g1;
    }
    __syncthreads();
    if (blockIdx.x == 0 && blockIdx.y == 0 && b == 0 && tid == 0) {
        float imp[E], ld[E];
        #pragma unroll
        for (int e = 0; e < E; ++e) { imp[e] = 0.0f; ld[e] = 0.0f; }
        for (int bb = 0; bb < B; ++bb)
            #pragma unroll
            for (int e = 0; e < E; ++e) {
                float g = lg[bb][e];
                imp[e] += g;
                if (g > 0.0f) ld[e] += 1.0f;
            }
        float mi = 0.0f, mld = 0.0f;
        #pragma unroll
        for (int e = 0; e < E; ++e) { mi += imp[e]; mld += ld[e]; }
        mi *= (1.0f / E); mld *= (1.0f / E);
        float vi = 0.0f, vl = 0.0f;
        #pragma unroll
        for (int e = 0; e < E; ++e) {
            float di = imp[e] - mi, dl = ld[e] - mld;
            vi += di * di; vl += dl * dl;
        }
        vi *= (1.0f / (E - 1)); vl *= (1.0f / (E - 1));
        out[NTOT] = (vi / (mi * mi + 1e-10f) + vl / (mld * mld + 1e-10f)) * 0.01f;
    }

    // ---- phase 1: all 3 silu planes -> gtile, then ONE barrier ----
    #pragma unroll
    for (int slot = 0; slot < 2; ++slot) {
        if (slot && p1 < 0) continue;
        const int pix = slot ? p1 : p0;
        const bool vv = slot ? vv1 : vv0;
        const u32* pk = slot ? pk1 : pk0;
        #pragma unroll
        for (int p = 0; p < 3; ++p) {
            u32 r[16];
            if (vv) {
                #pragma unroll
                for (int cc = 0; cc < 16; ++cc) {
                    float tl = __uint_as_float(pk[cc] << 16);
                    float th = __uint_as_float(pk[cc] & 0xffff0000u);
                    float ul, uh;
                    if (p == 0) { ul = tl; uh = th; }
                    else if (p == 1) { ul = fmaf(tl, tl, -beta2); uh = fmaf(th, th, -beta2); }
                    else { ul = tl * fmaf(tl, tl, -beta23); uh = th * fmaf(th, th, -beta23); }
                    u32 gl = __float_as_uint(silu(ul)) + 0x8000u;   // round-half-up
                    u32 gh = __float_as_uint(silu(uh)) + 0x8000u;
                    r[cc] = (gl >> 16) | (gh & 0xffff0000u);
                }
            } else {
                #pragma unroll
                for (int cc = 0; cc < 16; ++cc) r[cc] = 0u;
            }
            uint4* dst = (uint4*)&gtile[p][pix * GSTR];
            dst[0] = *(const uint4*)&r[0];
            dst[1] = *(const uint4*)&r[4];
            dst[2] = *(const uint4*)&r[8];
            dst[3] = *(const uint4*)&r[12];
        }
    }
    __syncthreads();

    // ---- phase 2: 648 MFMA per wave, no barriers ----
    f32x4 acc[4][2];
    #pragma unroll
    for (int a = 0; a < 4; ++a) {
        acc[a][0] = (f32x4){0.0f, 0.0f, 0.0f, 0.0f};
        acc[a][1] = (f32x4){0.0f, 0.0f, 0.0f, 0.0f};
    }
    #pragma unroll
    for (int p = 0; p < 3; ++p) {
        const u16* wf = wfrag + (size_t)p * 9216;
        #pragma unroll
        for (int dx = 0; dx < 3; ++dx) {
            bf16x8 bf[3][2];
            #pragma unroll
            for (int dyi = 0; dyi < 3; ++dyi) {
                const int tap = dyi * 3 + dx;
                bf[dyi][0] = *(const bf16x8*)(wf + ((size_t)(tap * 2 + 0) * 64 + lane) * 8);
                bf[dyi][1] = *(const bf16x8*)(wf + ((size_t)(tap * 2 + 1) * 64 + lane) * 8);
            }
            #pragma unroll
            for (int rl = 0; rl < 6; ++rl) {
                const bf16x8 af = *(const bf16x8*)
                    &gtile[p][(((w << 2) + rl) * 18 + ml + dx) * GSTR + (q << 3)];
                #pragma unroll
                for (int dyi = 0; dyi < 3; ++dyi) {
                    const int a = rl - dyi;
                    if (a >= 0 && a < 4) {
                        acc[a][0] = __builtin_amdgcn_mfma_f32_16x16x32_bf16(af, bf[dyi][0], acc[a][0], 0, 0, 0);
                        acc[a][1] = __builtin_amdgcn_mfma_f32_16x16x32_bf16(af, bf[dyi][1], acc[a][1], 0, 0, 0);
                    }
                }
            }
        }
    }

    // ---- epilogue: P0 bias (border-aware) + scale + store ----
    const float sc = scl[b];
    const bool interior = (blockIdx.x > 0) && (blockIdx.x < 11) &&
                          (blockIdx.y > 0) && (blockIdx.y < 11);
    #pragma unroll
    for (int half = 0; half < 2; ++half) {
        const int co = half * 16 + ml;
        const float bfull = SILU1 * Ssum[co];
        #pragma unroll
        for (int a = 0; a < 4; ++a) {
            const int y = gy0 + (w << 2) + a;
            float ov[4];
            #pragma unroll
            for (int r = 0; r < 4; ++r) {
                float bias = bfull;
                if (!interior) {
                    const int xg = gx0 + (q << 2) + r;
                    bias = 0.0f;
                    #pragma unroll
                    for (int k = 0; k < 9; ++k) {
                        int yy = y + k / 3 - 1, xx = xg + k % 3 - 1;
                        if ((unsigned)yy < (unsigned)H && (unsigned)xx < (unsigned)W)
                            bias += Sk[k * 32 + co];
                    }
                    bias *= SILU1;
                }
                ov[r] = (acc[a][half][r] + bias) * sc;
            }
            *(float4*)&out[((size_t)(b * CO + co) * H + y) * W + gx0 + (q << 2)] = *(float4*)ov;
        }
    }
}

extern "C" void kernel_launch(void* const* d_in, const int* in_sizes, int n_in,
                              void* d_out, int out_size, void* d_ws, size_t ws_size,
                              hipStream_t stream) {
    const float* x  = (const float*)d_in[0];
    const float* wg = (const float*)d_in[1];
    const float* pw = (const float*)d_in[2];
    const float* bw = (const float*)d_in[3];
    float* out = (float*)d_out;
    char* ws = (char*)d_ws;
    u16*   t_ws   = (u16*)ws;
    float* gate_x = (float*)(ws + GX_OFF);
    float* Sk     = (float*)(ws + SK_OFF);
    float* Ssum   = (float*)(ws + SS_OFF);
    u16*   wfrag  = (u16*)(ws + WF_OFF);

    init_gate<<<dim3(1), 512, 0, stream>>>(gate_x);
    stage1<<<dim3(H, B), 192, 0, stream>>>(x, t_ws, gate_x);
    prep<<<dim3(109), 256, 0, stream>>>(pw, Sk, Ssum, wfrag);
    conv_mfma<<<dim3(12, 12, B), 256, 0, stream>>>(t_ws, wfrag, bw, gate_x, wg, Sk, Ssum, out);
}